// Round 1
// baseline (1614.489 us; speedup 1.0000x reference)
//
#include <hip/hip_runtime.h>
#include <math.h>

#define T_STEPS 40
#define BATCH   32
#define DIN     57600
// TT core offsets inside kernel[] (floats)
#define OFF0 2848
#define OFF1 1568
#define OFF2 288
#define OFF3 0

// ---------------------------------------------------------------------------
// Phase 0: transpose recurrent_kernel (256 x 768) -> rkT (768 x 256)
// ---------------------------------------------------------------------------
__global__ void transpose_rk(const float* __restrict__ rk, float* __restrict__ rkT) {
    int idx = blockIdx.x * 256 + threadIdx.x;   // idx = c*256 + i
    if (idx < 768 * 256) {
        int c = idx >> 8;
        int i = idx & 255;
        rkT[idx] = rk[i * 768 + c];
    }
}

// ---------------------------------------------------------------------------
// Phase 1: TT-apply for every (b,t) sample. One workgroup per sample.
// x sample viewed as [i0=8][i1=20][i2=20][i3=18] (i3 fastest).
// Output mx[b*T+t][c], c = j0*64 + j1*16 + j2*4 + j3, plus bias.
// ---------------------------------------------------------------------------
__global__ __launch_bounds__(256) void tt_kernel(const float* __restrict__ x,
                                                 const float* __restrict__ ker,
                                                 const float* __restrict__ bias,
                                                 float* __restrict__ mx) {
    __shared__ float kers[3232];
    __shared__ float xt[1440];   // 4 (i1) x 20 (i2) x 18 (i3)
    __shared__ float t3[1280];   // 4 (i1) x 20 (i2) x 16 (r3*4+j3)
    __shared__ float o2[1280];   // 20 (i1) x 4 (j3) x 16 (r2*4+j2)   (current i0)
    __shared__ float o1[2048];   // 8 (i0) x 16 (j2*4+j3) x 16 (r1*4+j1)

    const int tid = threadIdx.x;
    const int blk = blockIdx.x;            // b*T + t
    const float* xs = x + (size_t)blk * DIN;

    for (int i = tid; i < 3232; i += 256) kers[i] = ker[i];
    __syncthreads();

    for (int i0 = 0; i0 < 8; ++i0) {
        for (int tile = 0; tile < 5; ++tile) {       // i1 = tile*4 + q
            // ---- load 4 (i0,i1) groups = 1440 contiguous floats ----
            const float* xp = xs + (i0 * 20 + tile * 4) * 360;
            for (int i = tid; i < 1440; i += 256) xt[i] = xp[i];
            __syncthreads();

            // ---- stage 3: t3[q][i2][r3*4+j3] = sum_i3 x * core3[i3][rc] ----
            for (int idx = tid; idx < 1280; idx += 256) {
                int rc  = idx & 15;
                int row = idx >> 4;                  // q*20 + i2
                const float* xr = &xt[row * 18];
                const float* c3 = &kers[OFF3 + rc];
                float acc = 0.f;
                #pragma unroll
                for (int i3 = 0; i3 < 18; ++i3) acc += xr[i3] * c3[i3 * 16];
                t3[idx] = acc;
            }
            __syncthreads();

            // ---- stage 2: o2[i1][j3][rc2] = sum_{i2,r3} t3 * core2 ----
            {
                int idx = tid;                        // ((q*4 + j3)*16 + rc2)
                int rc2 = idx & 15;
                int j3  = (idx >> 4) & 3;
                int q   = idx >> 6;
                const float* c2  = &kers[OFF2 + rc2];
                const float* t3p = &t3[q * 320 + j3]; // + (i2*4+r3)*4
                float acc = 0.f;
                #pragma unroll 4
                for (int ir = 0; ir < 80; ++ir)       // ir = i2*4 + r3
                    acc += t3p[ir * 4] * c2[ir * 16];
                o2[((tile * 4 + q) * 4 + j3) * 16 + rc2] = acc;
            }
            __syncthreads();
        }

        // ---- stage 1: o1[i0][j2*4+j3][rc1] = sum_{i1,r2} o2 * core1 ----
        {
            int idx = tid;                            // (j2*4 + j3)*16 + rc1
            int rc1 = idx & 15;
            int j3  = (idx >> 4) & 3;
            int j2  = idx >> 6;
            float acc = 0.f;
            #pragma unroll 4
            for (int ir = 0; ir < 80; ++ir) {         // ir = i1*4 + r2
                int i1 = ir >> 2, r2 = ir & 3;
                acc += o2[(i1 * 4 + j3) * 16 + r2 * 4 + j2] * kers[OFF1 + ir * 16 + rc1];
            }
            o1[(i0 * 16 + (j2 * 4 + j3)) * 16 + rc1] = acc;
        }
        __syncthreads();
    }

    // ---- stage 0: mx[c] = sum_{i0,r1} o1 * core0 + bias ----
    for (int c = tid; c < 768; c += 256) {
        int j3 = c & 3, j2 = (c >> 2) & 3, j1 = (c >> 4) & 3, j0 = c >> 6;
        float acc = 0.f;
        #pragma unroll
        for (int ir = 0; ir < 32; ++ir) {             // ir = i0*4 + r1
            int i0 = ir >> 2, r1 = ir & 3;
            acc += o1[(i0 * 16 + (j2 * 4 + j3)) * 16 + (r1 * 4 + j1)]
                 * kers[OFF0 + ir * 12 + j0];
        }
        mx[(size_t)blk * 768 + c] = acc + bias[c];
    }
}

// ---------------------------------------------------------------------------
// Phase 2: sequential GRU. One workgroup per batch sample, 512 threads.
// rkT is [768][256] (row = output column). Classifier fused at the end.
// ---------------------------------------------------------------------------
__global__ __launch_bounds__(512) void gru_kernel(const float* __restrict__ mx,
                                                  const float* __restrict__ rkT,
                                                  const float* __restrict__ cls_w,
                                                  const float* __restrict__ cls_b,
                                                  float* __restrict__ out) {
    __shared__ float h[256];
    __shared__ float zbuf[256];
    __shared__ float rh[256];
    __shared__ float hhp[256];

    const int tid = threadIdx.x;
    const int b = blockIdx.x;
    if (tid < 256) h[tid] = 0.f;
    __syncthreads();

    const float* mxb = mx + (size_t)b * T_STEPS * 768;

    for (int t = 0; t < T_STEPS; ++t) {
        const float* mxt = mxb + t * 768;

        // ---- substep A: columns 0..511 -> z / r ----
        {
            const float4* w  = (const float4*)(rkT + tid * 256);
            const float4* h4 = (const float4*)h;
            float acc = 0.f;
            #pragma unroll 8
            for (int i = 0; i < 64; ++i) {
                float4 wv = w[i];
                float4 hv = h4[i];
                acc += wv.x * hv.x + wv.y * hv.y + wv.z * hv.z + wv.w * hv.w;
            }
            float v = mxt[tid] + acc;
            float g = fminf(fmaxf(v * (1.f / 6.f) + 0.5f, 0.f), 1.f);
            if (tid < 256) zbuf[tid] = g;
            else           rh[tid - 256] = g * h[tid - 256];
        }
        __syncthreads();

        // ---- substep B: 256 hh columns, 2 threads per column ----
        {
            int c = tid & 255;
            int half = tid >> 8;
            const float4* w  = (const float4*)(rkT + (512 + c) * 256 + half * 128);
            const float4* r4 = (const float4*)(rh + half * 128);
            float acc = 0.f;
            #pragma unroll 8
            for (int i = 0; i < 32; ++i) {
                float4 wv = w[i];
                float4 rv = r4[i];
                acc += wv.x * rv.x + wv.y * rv.y + wv.z * rv.z + wv.w * rv.w;
            }
            if (half) hhp[c] = acc;
            __syncthreads();
            if (!half) {
                float hhv = tanhf(mxt[512 + c] + acc + hhp[c]);
                float z = zbuf[c];
                h[c] = z * h[c] + (1.f - z) * hhv;
            }
        }
        __syncthreads();
    }

    // ---- classifier: out[b][o] = h . cls_w[o] + cls_b[o] ----
    if (tid < 11) {
        float acc = cls_b[tid];
        const float* w = cls_w + tid * 256;
        #pragma unroll 4
        for (int i = 0; i < 256; ++i) acc += h[i] * w[i];
        out[b * 11 + tid] = acc;
    }
}

// ---------------------------------------------------------------------------
extern "C" void kernel_launch(void* const* d_in, const int* in_sizes, int n_in,
                              void* d_out, int out_size, void* d_ws, size_t ws_size,
                              hipStream_t stream) {
    const float* x     = (const float*)d_in[0];   // [32][40][57600]
    const float* ker   = (const float*)d_in[1];   // [3232]
    const float* rk    = (const float*)d_in[2];   // [256][768]
    const float* bias  = (const float*)d_in[3];   // [768]
    const float* cls_w = (const float*)d_in[4];   // [11][256]
    const float* cls_b = (const float*)d_in[5];   // [11]
    float* outp = (float*)d_out;                  // [32][11]

    float* mx  = (float*)d_ws;                               // 1280*768 floats
    float* rkT = mx + (size_t)BATCH * T_STEPS * 768;         // 768*256 floats

    transpose_rk<<<768, 256, 0, stream>>>(rk, rkT);
    tt_kernel<<<BATCH * T_STEPS, 256, 0, stream>>>(x, ker, bias, mx);
    gru_kernel<<<BATCH, 512, 0, stream>>>(mx, rkT, cls_w, cls_b, outp);
}

// Round 2
// 788.348 us; speedup vs baseline: 2.0479x; 2.0479x over previous
//
#include <hip/hip_runtime.h>
#include <math.h>

#define T_STEPS 40
#define BATCH   32
#define DIN     57600
// TT core offsets inside kernel[] (floats)
#define OFF0 2848
#define OFF1 1568
#define OFF2 288
#define OFF3 0

typedef _Float16 h2 __attribute__((ext_vector_type(2)));

__device__ __forceinline__ float dot2(h2 a, h2 b, float c) {
#if __has_builtin(__builtin_amdgcn_fdot2)
    return __builtin_amdgcn_fdot2(a, b, c, false);
#else
    return c + (float)a.x * (float)b.x + (float)a.y * (float)b.y;
#endif
}

// ---------------------------------------------------------------------------
// Phase 1: TT-apply, one WG (256 thr) per (b,t) sample.
// x sample viewed as [i0=8][i1=20][i2=20][i3=18]. Weight columns live in
// registers; x rows are read straight from global (coalescer merges the
// 4 threads sharing a row); all hot LDS reads are b128 feeding 4 FMAs.
// ---------------------------------------------------------------------------
__global__ __launch_bounds__(256, 2) void tt_kernel(const float* __restrict__ x,
                                                    const float* __restrict__ ker,
                                                    const float* __restrict__ bias,
                                                    float* __restrict__ mx) {
    __shared__ __align__(16) float t3[6400];   // [400 rows][16]  (r3*4+j3)
    __shared__ __align__(16) float o2[1280];   // [i1*4+j3][16]   (r2*4+j2)
    __shared__ __align__(16) float o1[2048];   // [i0*16+j23][16] (r1*4+j1)
    __shared__ __align__(16) float part1[1024];// [j23*16+rc1][4] (q)

    const int tid = threadIdx.x;
    const float* xs = x + (size_t)blockIdx.x * DIN;

    // ---- persistent register weights ----
    const int rcg = tid & 3, rowgrp = tid >> 2;          // stage 3 mapping
    float c3r[18][4];
    #pragma unroll
    for (int i3 = 0; i3 < 18; ++i3)
        #pragma unroll
        for (int k = 0; k < 4; ++k)
            c3r[i3][k] = ker[OFF3 + i3 * 16 + rcg * 4 + k];

    const int rc2 = tid & 15, i1slot = tid >> 4;         // stage 2 mapping
    float c2r[80];
    #pragma unroll
    for (int ir = 0; ir < 80; ++ir) c2r[ir] = ker[OFF2 + ir * 16 + rc2];

    const int rc1 = tid & 15, j3s = (tid >> 4) & 3, qs = tid >> 6; // stage 1
    float c1r[20];
    #pragma unroll
    for (int t = 0; t < 20; ++t)                          // ir = qs*20+t contiguous
        c1r[t] = ker[OFF1 + (qs * 20 + t) * 16 + rc1];

    for (int i0 = 0; i0 < 8; ++i0) {
        // ---- stage 3: rows (i1,i2) from global, 4 rc-columns per thread ----
        const float* xp = xs + i0 * 7200;
        for (int r = rowgrp; r < 400; r += 64) {
            const float* xr = xp + r * 18;
            float xv[18];
            #pragma unroll
            for (int j = 0; j < 9; ++j) {
                float2 v = *(const float2*)(xr + 2 * j);
                xv[2 * j] = v.x; xv[2 * j + 1] = v.y;
            }
            float a0 = 0.f, a1 = 0.f, a2 = 0.f, a3 = 0.f;
            #pragma unroll
            for (int i3 = 0; i3 < 18; ++i3) {
                a0 = fmaf(xv[i3], c3r[i3][0], a0);
                a1 = fmaf(xv[i3], c3r[i3][1], a1);
                a2 = fmaf(xv[i3], c3r[i3][2], a2);
                a3 = fmaf(xv[i3], c3r[i3][3], a3);
            }
            *(float4*)&t3[r * 16 + rcg * 4] = make_float4(a0, a1, a2, a3);
        }
        __syncthreads();

        // ---- stage 2: one b128 feeds 4 j3-outputs; c2 column in regs ----
        for (int i1 = i1slot; i1 < 20; i1 += 16) {
            float b0 = 0.f, b1 = 0.f, b2 = 0.f, b3 = 0.f;
            #pragma unroll
            for (int ii = 0; ii < 80; ++ii) {            // ii = i2*4 + r3
                const float4 tv = *(const float4*)&t3[(i1 * 20 + (ii >> 2)) * 16 + (ii & 3) * 4];
                const float w = c2r[ii];
                b0 = fmaf(tv.x, w, b0); b1 = fmaf(tv.y, w, b1);
                b2 = fmaf(tv.z, w, b2); b3 = fmaf(tv.w, w, b3);
            }
            o2[(i1 * 4 + 0) * 16 + rc2] = b0;
            o2[(i1 * 4 + 1) * 16 + rc2] = b1;
            o2[(i1 * 4 + 2) * 16 + rc2] = b2;
            o2[(i1 * 4 + 3) * 16 + rc2] = b3;
        }
        __syncthreads();

        // ---- stage 1: 4-way split reduction over (i1,r2); b128 feeds 4 j2 ----
        {
            float a0 = 0.f, a1 = 0.f, a2 = 0.f, a3 = 0.f;
            #pragma unroll
            for (int t = 0; t < 20; ++t) {
                const int ir = qs * 20 + t;              // i1*4 + r2
                const float4 ov = *(const float4*)&o2[((ir >> 2) * 4 + j3s) * 16 + (ir & 3) * 4];
                const float w = c1r[t];
                a0 = fmaf(ov.x, w, a0); a1 = fmaf(ov.y, w, a1);
                a2 = fmaf(ov.z, w, a2); a3 = fmaf(ov.w, w, a3);
            }
            part1[((0 * 4 + j3s) * 16 + rc1) * 4 + qs] = a0;
            part1[((1 * 4 + j3s) * 16 + rc1) * 4 + qs] = a1;
            part1[((2 * 4 + j3s) * 16 + rc1) * 4 + qs] = a2;
            part1[((3 * 4 + j3s) * 16 + rc1) * 4 + qs] = a3;
        }
        __syncthreads();
        {
            const float4 p = *(const float4*)&part1[tid * 4];
            o1[(i0 * 16 + (tid >> 4)) * 16 + (tid & 15)] = p.x + p.y + p.z + p.w;
        }
        __syncthreads();
    }

    // ---- stage 0: 3 output columns per thread, c0 from global (L1-hot) ----
    {
        const int j23 = tid & 15, j1 = (tid >> 4) & 3, j0g = tid >> 6;
        float acc0 = 0.f, acc1 = 0.f, acc2 = 0.f;
        #pragma unroll
        for (int ir = 0; ir < 32; ++ir) {                 // ir = i0*4 + r1
            const float ov = o1[((ir >> 2) * 16 + j23) * 16 + ((ir & 3) * 4 + j1)];
            acc0 = fmaf(ov, ker[OFF0 + ir * 12 + j0g * 3 + 0], acc0);
            acc1 = fmaf(ov, ker[OFF0 + ir * 12 + j0g * 3 + 1], acc1);
            acc2 = fmaf(ov, ker[OFF0 + ir * 12 + j0g * 3 + 2], acc2);
        }
        float* mrow = mx + (size_t)blockIdx.x * 768;
        const int c0i = (j0g * 3 + 0) * 64 + j1 * 16 + j23;
        const int c1i = (j0g * 3 + 1) * 64 + j1 * 16 + j23;
        const int c2i = (j0g * 3 + 2) * 64 + j1 * 16 + j23;
        mrow[c0i] = acc0 + bias[c0i];
        mrow[c1i] = acc1 + bias[c1i];
        mrow[c2i] = acc2 + bias[c2i];
    }
}

// ---------------------------------------------------------------------------
// Phase 2: sequential GRU, one WG (512 thr) per sample. ALL recurrent weights
// register-resident as fp16 (192 packed-h2 VGPRs/thread): each thread owns one
// z/r column (256 wts) + half an hh column (128 wts). h broadcast via LDS fp16.
// ---------------------------------------------------------------------------
__global__ __launch_bounds__(512, 2) void gru_kernel(const float* __restrict__ mx,
                                                     const float* __restrict__ rk,
                                                     const float* __restrict__ cls_w,
                                                     const float* __restrict__ cls_b,
                                                     float* __restrict__ out) {
    __shared__ float h32[256];
    __shared__ float zbuf[256];
    __shared__ float partB[256];
    __shared__ __align__(16) unsigned short h16[256];
    __shared__ __align__(16) unsigned short rh16[256];

    const int tid = threadIdx.x;
    const int b = blockIdx.x;

    // ---- load weights into registers (one-time, coalesced across threads) ----
    h2 wA[128];                      // column `tid` of rk[:, 0:512]
    #pragma unroll
    for (int j = 0; j < 128; ++j) {
        h2 w;
        w.x = (_Float16)rk[(2 * j) * 768 + tid];
        w.y = (_Float16)rk[(2 * j + 1) * 768 + tid];
        wA[j] = w;
    }
    const int cb = tid & 255, seg = tid >> 8;
    h2 wB[64];                       // rows [seg*128, seg*128+128) of col 512+cb
    #pragma unroll
    for (int j = 0; j < 64; ++j) {
        const int i = seg * 128 + 2 * j;
        h2 w;
        w.x = (_Float16)rk[i * 768 + 512 + cb];
        w.y = (_Float16)rk[(i + 1) * 768 + 512 + cb];
        wB[j] = w;
    }

    if (tid < 256) { h32[tid] = 0.f; h16[tid] = 0; }
    __syncthreads();

    const float* mxb = mx + (size_t)b * T_STEPS * 768;

    for (int t = 0; t < T_STEPS; ++t) {
        const float* mxt = mxb + t * 768;

        // ---- phase A: all 512 threads, one z/r column each ----
        {
            const float mval = mxt[tid];
            float acc = 0.f;
            const uint4* hp = (const uint4*)h16;         // 8 halves per read
            #pragma unroll
            for (int j = 0; j < 32; ++j) {
                const uint4 u = hp[j];
                acc = dot2(wA[4 * j + 0], __builtin_bit_cast(h2, u.x), acc);
                acc = dot2(wA[4 * j + 1], __builtin_bit_cast(h2, u.y), acc);
                acc = dot2(wA[4 * j + 2], __builtin_bit_cast(h2, u.z), acc);
                acc = dot2(wA[4 * j + 3], __builtin_bit_cast(h2, u.w), acc);
            }
            const float v = mval + acc;
            const float g = fminf(fmaxf(v * (1.f / 6.f) + 0.5f, 0.f), 1.f);
            if (tid < 256) zbuf[tid] = g;
            else {
                const float rhv = g * h32[tid - 256];
                ((_Float16*)rh16)[tid - 256] = (_Float16)rhv;
            }
        }
        __syncthreads();

        // ---- phase B: 2 threads per hh column (128 terms each) ----
        {
            float acc = 0.f;
            const uint4* rp = (const uint4*)rh16 + seg * 16;  // 128 halves/seg
            #pragma unroll
            for (int j = 0; j < 16; ++j) {
                const uint4 u = rp[j];
                acc = dot2(wB[4 * j + 0], __builtin_bit_cast(h2, u.x), acc);
                acc = dot2(wB[4 * j + 1], __builtin_bit_cast(h2, u.y), acc);
                acc = dot2(wB[4 * j + 2], __builtin_bit_cast(h2, u.z), acc);
                acc = dot2(wB[4 * j + 3], __builtin_bit_cast(h2, u.w), acc);
            }
            if (seg) partB[cb] = acc;
            __syncthreads();
            if (!seg) {
                const float s = mxt[512 + cb] + acc + partB[cb];
                const float hh = tanhf(s);
                const float z = zbuf[cb];
                const float hn = z * h32[cb] + (1.f - z) * hh;
                h32[cb] = hn;
                h16[cb] = __builtin_bit_cast(unsigned short, (_Float16)hn);
            }
        }
        __syncthreads();
    }

    // ---- classifier ----
    if (tid < 11) {
        float acc = cls_b[tid];
        const float* w = cls_w + tid * 256;
        #pragma unroll 4
        for (int i = 0; i < 256; ++i) acc = fmaf(h32[i], w[i], acc);
        out[b * 11 + tid] = acc;
    }
}

// ---------------------------------------------------------------------------
extern "C" void kernel_launch(void* const* d_in, const int* in_sizes, int n_in,
                              void* d_out, int out_size, void* d_ws, size_t ws_size,
                              hipStream_t stream) {
    const float* x     = (const float*)d_in[0];   // [32][40][57600]
    const float* ker   = (const float*)d_in[1];   // [3232]
    const float* rk    = (const float*)d_in[2];   // [256][768]
    const float* bias  = (const float*)d_in[3];   // [768]
    const float* cls_w = (const float*)d_in[4];   // [11][256]
    const float* cls_b = (const float*)d_in[5];   // [11]
    float* outp = (float*)d_out;                  // [32][11]

    float* mx = (float*)d_ws;                     // 1280*768 floats

    tt_kernel<<<BATCH * T_STEPS, 256, 0, stream>>>(x, ker, bias, mx);
    gru_kernel<<<BATCH, 512, 0, stream>>>(mx, rk, cls_w, cls_b, outp);
}

// Round 3
// 623.797 us; speedup vs baseline: 2.5882x; 1.2638x over previous
//
#include <hip/hip_runtime.h>
#include <math.h>

#define T_STEPS 40
#define BATCH   32
#define DIN     57600
// TT core offsets inside kernel[] (floats)
#define OFF0 2848
#define OFF1 1568
#define OFF2 288
#define OFF3 0
#define T3LD 20   // padded row stride of t3 (16 data + 4 pad)

typedef _Float16 h2 __attribute__((ext_vector_type(2)));
typedef unsigned short u16;

__device__ __forceinline__ float dot2(h2 a, h2 b, float c) {
#if __has_builtin(__builtin_amdgcn_fdot2)
    return __builtin_amdgcn_fdot2(a, b, c, false);
#else
    return c + (float)a.x * (float)b.x + (float)a.y * (float)b.y;
#endif
}

// ---------------------------------------------------------------------------
// Phase 0: mx[b][c] = bias[c]  (tt_kernel atomically accumulates on top)
// ---------------------------------------------------------------------------
__global__ void init_mx(const float* __restrict__ bias, float* __restrict__ mx) {
    mx[(size_t)blockIdx.x * 768 + threadIdx.x] = bias[threadIdx.x];
}

// ---------------------------------------------------------------------------
// Phase 1: TT-apply. One WG (256 thr) per (sample, i0): grid = 1280*8.
// Stages 3/2/1 are i0-independent; stage 0 (sum over i0,r1) via atomicAdd.
// x slice [i1=20][i2=20][i3=18] staged in LDS via coalesced float4 loads.
// Weight arrays are fully-unrolled-indexed -> guaranteed register-resident,
// and sequentially live (c3r dead before c2r loads, etc.).
// ---------------------------------------------------------------------------
__global__ __launch_bounds__(256, 2) void tt_kernel(const float* __restrict__ x,
                                                    const float* __restrict__ ker,
                                                    float* __restrict__ mx) {
    __shared__ __align__(16) float xt[7200];         // 28.8 KB
    __shared__ __align__(16) float t3[400 * T3LD];   // 32.0 KB (padded stride)
    __shared__ __align__(16) float o2[1280];         //  5.1 KB
    __shared__ __align__(16) float part1[1024];      //  4.1 KB
    __shared__ __align__(16) float o1s[256];         //  1.0 KB

    const int tid = threadIdx.x;
    const int sample = blockIdx.x >> 3;
    const int i0 = blockIdx.x & 7;
    const float* xp = x + (size_t)sample * DIN + i0 * 7200;

    // ---- coalesced stage of this (sample,i0) x-slice into LDS ----
    for (int i = tid; i < 1800; i += 256)
        ((float4*)xt)[i] = ((const float4*)xp)[i];

    // ---- stage-3 weights (live only through stage 3) ----
    const int rcg = tid & 3, rowgrp = tid >> 2;
    float c3r[18][4];
    #pragma unroll
    for (int i3 = 0; i3 < 18; ++i3)
        *(float4*)&c3r[i3][0] = *(const float4*)&ker[OFF3 + i3 * 16 + rcg * 4];
    __syncthreads();

    // ---- stage 3: 4 threads/row, 4 rc columns each; rows from LDS ----
    for (int r = rowgrp; r < 400; r += 64) {
        float xv[18];
        #pragma unroll
        for (int j = 0; j < 9; ++j) {
            float2 v = *(const float2*)&xt[r * 18 + 2 * j];
            xv[2 * j] = v.x; xv[2 * j + 1] = v.y;
        }
        float a0 = 0.f, a1 = 0.f, a2 = 0.f, a3 = 0.f;
        #pragma unroll
        for (int i3 = 0; i3 < 18; ++i3) {
            a0 = fmaf(xv[i3], c3r[i3][0], a0);
            a1 = fmaf(xv[i3], c3r[i3][1], a1);
            a2 = fmaf(xv[i3], c3r[i3][2], a2);
            a3 = fmaf(xv[i3], c3r[i3][3], a3);
        }
        *(float4*)&t3[r * T3LD + rcg * 4] = make_float4(a0, a1, a2, a3);
    }
    __syncthreads();

    // ---- stage 2: c2 column in regs (FULL unroll -> no scratch) ----
    {
        const int rc2 = tid & 15, i1slot = tid >> 4;
        float c2r[80];
        #pragma unroll
        for (int ir = 0; ir < 80; ++ir) c2r[ir] = ker[OFF2 + ir * 16 + rc2];

        for (int i1 = i1slot; i1 < 20; i1 += 16) {
            float b0 = 0.f, b1 = 0.f, b2 = 0.f, b3 = 0.f;
            #pragma unroll
            for (int ii = 0; ii < 80; ++ii) {        // ii = i2*4 + r3
                const float4 tv = *(const float4*)&t3[(i1 * 20 + (ii >> 2)) * T3LD + (ii & 3) * 4];
                const float w = c2r[ii];
                b0 = fmaf(tv.x, w, b0); b1 = fmaf(tv.y, w, b1);
                b2 = fmaf(tv.z, w, b2); b3 = fmaf(tv.w, w, b3);
            }
            o2[(i1 * 4 + 0) * 16 + rc2] = b0;
            o2[(i1 * 4 + 1) * 16 + rc2] = b1;
            o2[(i1 * 4 + 2) * 16 + rc2] = b2;
            o2[(i1 * 4 + 3) * 16 + rc2] = b3;
        }
    }
    __syncthreads();

    // ---- stage 1: 4-way split over (i1,r2); c1 segment in regs ----
    {
        const int rc1 = tid & 15, j3s = (tid >> 4) & 3, qs = tid >> 6;
        float c1r[20];
        #pragma unroll
        for (int t = 0; t < 20; ++t)
            c1r[t] = ker[OFF1 + (qs * 20 + t) * 16 + rc1];

        float a0 = 0.f, a1 = 0.f, a2 = 0.f, a3 = 0.f;
        #pragma unroll
        for (int t = 0; t < 20; ++t) {
            const int ir = qs * 20 + t;              // i1*4 + r2
            const float4 ov = *(const float4*)&o2[((ir >> 2) * 4 + j3s) * 16 + (ir & 3) * 4];
            const float w = c1r[t];
            a0 = fmaf(ov.x, w, a0); a1 = fmaf(ov.y, w, a1);
            a2 = fmaf(ov.z, w, a2); a3 = fmaf(ov.w, w, a3);
        }
        part1[((0 * 4 + j3s) * 16 + rc1) * 4 + qs] = a0;
        part1[((1 * 4 + j3s) * 16 + rc1) * 4 + qs] = a1;
        part1[((2 * 4 + j3s) * 16 + rc1) * 4 + qs] = a2;
        part1[((3 * 4 + j3s) * 16 + rc1) * 4 + qs] = a3;
    }
    __syncthreads();
    {
        const float4 p = *(const float4*)&part1[tid * 4];
        o1s[tid] = p.x + p.y + p.z + p.w;            // [j23=tid>>4][rc1=tid&15]
    }
    __syncthreads();

    // ---- stage 0 (this i0's contribution): 3 columns/thread, atomic ----
    {
        const int j23 = tid & 15, j1 = (tid >> 4) & 3, j0g = tid >> 6;
        float a0 = 0.f, a1 = 0.f, a2 = 0.f;
        #pragma unroll
        for (int r1 = 0; r1 < 4; ++r1) {
            const float ov = o1s[j23 * 16 + r1 * 4 + j1];
            const int kb = OFF0 + (i0 * 4 + r1) * 12 + j0g * 3;
            a0 = fmaf(ov, ker[kb + 0], a0);
            a1 = fmaf(ov, ker[kb + 1], a1);
            a2 = fmaf(ov, ker[kb + 2], a2);
        }
        float* mrow = mx + (size_t)sample * 768;
        atomicAdd(&mrow[(j0g * 3 + 0) * 64 + j1 * 16 + j23], a0);
        atomicAdd(&mrow[(j0g * 3 + 1) * 64 + j1 * 16 + j23], a1);
        atomicAdd(&mrow[(j0g * 3 + 2) * 64 + j1 * 16 + j23], a2);
    }
}

// ---------------------------------------------------------------------------
// Phase 2: sequential GRU, one WG (512 thr) per sample.
// z/r weights: fp16 registers (128 h2/thread -> VGPR-safe).
// hh weights: fp16 LDS, padded column stride 264 halves -> conflict-free b128.
// ---------------------------------------------------------------------------
__global__ __launch_bounds__(512) void gru_kernel(const float* __restrict__ mx,
                                                  const float* __restrict__ rk,
                                                  const float* __restrict__ cls_w,
                                                  const float* __restrict__ cls_b,
                                                  float* __restrict__ out) {
    __shared__ __align__(16) u16 wb[256 * 264];      // 132 KB hh weights
    __shared__ float h32[256];
    __shared__ float zbuf[256];
    __shared__ float partB[256];
    __shared__ __align__(16) u16 h16[256];
    __shared__ __align__(16) u16 rh16[256];

    const int tid = threadIdx.x;
    const int b = blockIdx.x;
    const int cb = tid & 255, seg = tid >> 8;

    // ---- z/r column `tid` -> registers (fp16), coalesced across lanes ----
    h2 wA[128];
    #pragma unroll
    for (int j = 0; j < 128; ++j) {
        h2 w;
        w.x = (_Float16)rk[(2 * j) * 768 + tid];
        w.y = (_Float16)rk[(2 * j + 1) * 768 + tid];
        wA[j] = w;
    }
    // ---- hh weights -> LDS (column-major, padded stride 264 halves) ----
    for (int k2 = 0; k2 < 128; ++k2) {
        const int k = seg * 128 + k2;
        wb[cb * 264 + k] = __builtin_bit_cast(u16, (_Float16)rk[k * 768 + 512 + cb]);
    }
    if (tid < 256) { h32[tid] = 0.f; h16[tid] = 0; }
    __syncthreads();

    const float* mxb = mx + (size_t)b * T_STEPS * 768;
    float mA = mxb[tid];             // phase-A operand, prefetched
    float mB = mxb[512 + cb];        // phase-B operand, prefetched

    for (int t = 0; t < T_STEPS; ++t) {
        // prefetch next step's mx operands under this step's compute
        float mA_n = 0.f, mB_n = 0.f;
        if (t + 1 < T_STEPS) {
            const float* nx = mxb + (t + 1) * 768;
            mA_n = nx[tid];
            mB_n = nx[512 + cb];
        }

        // ---- phase A: all 512 threads, one z/r column each ----
        {
            float acc = 0.f;
            const uint4* hp = (const uint4*)h16;     // uniform -> broadcast
            #pragma unroll
            for (int j = 0; j < 32; ++j) {
                const uint4 u = hp[j];
                acc = dot2(wA[4 * j + 0], __builtin_bit_cast(h2, u.x), acc);
                acc = dot2(wA[4 * j + 1], __builtin_bit_cast(h2, u.y), acc);
                acc = dot2(wA[4 * j + 2], __builtin_bit_cast(h2, u.z), acc);
                acc = dot2(wA[4 * j + 3], __builtin_bit_cast(h2, u.w), acc);
            }
            const float v = mA + acc;
            const float g = fminf(fmaxf(v * (1.f / 6.f) + 0.5f, 0.f), 1.f);
            if (tid < 256) zbuf[tid] = g;
            else {
                ((_Float16*)rh16)[cb] = (_Float16)(g * h32[cb]);
            }
        }
        __syncthreads();

        // ---- phase B: 2 threads per hh column; weights from LDS ----
        {
            float acc = 0.f;
            const uint4* wp = (const uint4*)(wb + cb * 264 + seg * 128);
            const uint4* rp = (const uint4*)rh16 + seg * 16;
            #pragma unroll
            for (int j = 0; j < 16; ++j) {
                const uint4 w = wp[j];
                const uint4 r = rp[j];
                acc = dot2(__builtin_bit_cast(h2, w.x), __builtin_bit_cast(h2, r.x), acc);
                acc = dot2(__builtin_bit_cast(h2, w.y), __builtin_bit_cast(h2, r.y), acc);
                acc = dot2(__builtin_bit_cast(h2, w.z), __builtin_bit_cast(h2, r.z), acc);
                acc = dot2(__builtin_bit_cast(h2, w.w), __builtin_bit_cast(h2, r.w), acc);
            }
            if (seg) partB[cb] = acc;
            __syncthreads();
            if (!seg) {
                const float s = mB + acc + partB[cb];
                const float hh = tanhf(s);
                const float z = zbuf[cb];
                const float hn = z * h32[cb] + (1.f - z) * hh;
                h32[cb] = hn;
                h16[cb] = __builtin_bit_cast(u16, (_Float16)hn);
            }
        }
        __syncthreads();
        mA = mA_n; mB = mB_n;
    }

    // ---- classifier ----
    if (tid < 11) {
        float acc = cls_b[tid];
        const float* w = cls_w + tid * 256;
        #pragma unroll 4
        for (int i = 0; i < 256; ++i) acc = fmaf(h32[i], w[i], acc);
        out[b * 11 + tid] = acc;
    }
}

// ---------------------------------------------------------------------------
extern "C" void kernel_launch(void* const* d_in, const int* in_sizes, int n_in,
                              void* d_out, int out_size, void* d_ws, size_t ws_size,
                              hipStream_t stream) {
    const float* x     = (const float*)d_in[0];   // [32][40][57600]
    const float* ker   = (const float*)d_in[1];   // [3232]
    const float* rk    = (const float*)d_in[2];   // [256][768]
    const float* bias  = (const float*)d_in[3];   // [768]
    const float* cls_w = (const float*)d_in[4];   // [11][256]
    const float* cls_b = (const float*)d_in[5];   // [11]
    float* outp = (float*)d_out;                  // [32][11]

    float* mx = (float*)d_ws;                     // 1280*768 floats

    init_mx<<<BATCH * T_STEPS, 768, 0, stream>>>(bias, mx);
    tt_kernel<<<BATCH * T_STEPS * 8, 256, 0, stream>>>(x, ker, mx);
    gru_kernel<<<BATCH, 512, 0, stream>>>(mx, rk, cls_w, cls_b, outp);
}

// Round 4
// 618.537 us; speedup vs baseline: 2.6102x; 1.0085x over previous
//
#include <hip/hip_runtime.h>
#include <math.h>

#define T_STEPS 40
#define BATCH   32
#define DIN     57600
// TT core offsets inside kernel[] (floats)
#define OFF0 2848
#define OFF1 1568
#define OFF2 288
#define OFF3 0
#define T3LD 20   // padded row stride of t3 (16 data + 4 pad)

typedef _Float16 h2 __attribute__((ext_vector_type(2)));
typedef unsigned short u16;

__device__ __forceinline__ float dot2(h2 a, h2 b, float c) {
#if __has_builtin(__builtin_amdgcn_fdot2)
    return __builtin_amdgcn_fdot2(a, b, c, false);
#else
    return c + (float)a.x * (float)b.x + (float)a.y * (float)b.y;
#endif
}

// ---------------------------------------------------------------------------
// Phase 0: mx[b][c] = bias[c]  (tt_kernel atomically accumulates on top)
// ---------------------------------------------------------------------------
__global__ void init_mx(const float* __restrict__ bias, float* __restrict__ mx) {
    mx[(size_t)blockIdx.x * 768 + threadIdx.x] = bias[threadIdx.x];
}

// ---------------------------------------------------------------------------
// Phase 1: TT-apply. One WG (256 thr) per (sample, i0, i1-half): grid = 20480.
// LDS ~38.9 KB -> 4 WGs/CU (16 waves) for latency hiding.
// Stage chain: x-slice -> t3 (core3) -> o2 (core2) -> o1 partial (core1)
//              -> atomicAdd into mx (core0), linear in the i0/i1 splits.
// ---------------------------------------------------------------------------
__global__ __launch_bounds__(256, 4) void tt_kernel(const float* __restrict__ x,
                                                    const float* __restrict__ ker,
                                                    float* __restrict__ mx) {
    __shared__ __align__(16) float xt[3600];          // 14.4 KB: [i1loc=10][i2=20][i3=18]
    __shared__ __align__(16) float t3[200 * T3LD];    // 16.0 KB: [row][16+pad]
    __shared__ __align__(16) float o2[800];           //  3.2 KB: [i1loc*4+j3][20] (16 data)
    __shared__ __align__(16) float part1T[4 * 260];   //  4.2 KB: [qs][j23*16+rc1]
    __shared__ __align__(16) float o1s[256];          //  1.0 KB: [j23][rc1]

    const int tid = threadIdx.x;
    const int sample = blockIdx.x >> 4;
    const int i0     = (blockIdx.x >> 1) & 7;
    const int half   = blockIdx.x & 1;
    const float* xp = x + (size_t)sample * DIN + i0 * 7200 + half * 3600;

    // ---- coalesced stage of the half-slice into LDS ----
    for (int i = tid; i < 900; i += 256)
        ((float4*)xt)[i] = ((const float4*)xp)[i];

    // ---- stage-3 weights (live only through stage 3) ----
    const int rcg = tid & 3, rowgrp = tid >> 2;
    float c3r[18][4];
    #pragma unroll
    for (int i3 = 0; i3 < 18; ++i3)
        *(float4*)&c3r[i3][0] = *(const float4*)&ker[OFF3 + i3 * 16 + rcg * 4];
    __syncthreads();

    // ---- stage 3: 4 threads/row, 4 rc columns each ----
    for (int r = rowgrp; r < 200; r += 64) {
        float xv[18];
        #pragma unroll
        for (int j = 0; j < 9; ++j) {
            float2 v = *(const float2*)&xt[r * 18 + 2 * j];
            xv[2 * j] = v.x; xv[2 * j + 1] = v.y;
        }
        float a0 = 0.f, a1 = 0.f, a2 = 0.f, a3 = 0.f;
        #pragma unroll
        for (int i3 = 0; i3 < 18; ++i3) {
            a0 = fmaf(xv[i3], c3r[i3][0], a0);
            a1 = fmaf(xv[i3], c3r[i3][1], a1);
            a2 = fmaf(xv[i3], c3r[i3][2], a2);
            a3 = fmaf(xv[i3], c3r[i3][3], a3);
        }
        *(float4*)&t3[r * T3LD + rcg * 4] = make_float4(a0, a1, a2, a3);
    }
    __syncthreads();

    // ---- stage 2: c2 column in regs (full unroll) ----
    {
        const int rc2 = tid & 15, i1slot = tid >> 4;
        float c2r[80];
        #pragma unroll
        for (int ir = 0; ir < 80; ++ir) c2r[ir] = ker[OFF2 + ir * 16 + rc2];

        if (i1slot < 10) {
            const int i1 = i1slot;
            float b0 = 0.f, b1 = 0.f, b2 = 0.f, b3 = 0.f;
            #pragma unroll
            for (int ii = 0; ii < 80; ++ii) {         // ii = i2*4 + r3
                const float4 tv = *(const float4*)&t3[(i1 * 20 + (ii >> 2)) * T3LD + (ii & 3) * 4];
                const float w = c2r[ii];
                b0 = fmaf(tv.x, w, b0); b1 = fmaf(tv.y, w, b1);
                b2 = fmaf(tv.z, w, b2); b3 = fmaf(tv.w, w, b3);
            }
            o2[(i1 * 4 + 0) * 20 + rc2] = b0;
            o2[(i1 * 4 + 1) * 20 + rc2] = b1;
            o2[(i1 * 4 + 2) * 20 + rc2] = b2;
            o2[(i1 * 4 + 3) * 20 + rc2] = b3;
        }
    }
    __syncthreads();

    // ---- stage 1: 4-way split over the 40 (i1loc,r2) terms ----
    {
        const int rc1 = tid & 15, j3s = (tid >> 4) & 3, qs = tid >> 6;
        float c1r[10];
        #pragma unroll
        for (int t = 0; t < 10; ++t)
            c1r[t] = ker[OFF1 + (half * 40 + qs * 10 + t) * 16 + rc1];

        float a0 = 0.f, a1 = 0.f, a2 = 0.f, a3 = 0.f;
        #pragma unroll
        for (int t = 0; t < 10; ++t) {
            const int ir = qs * 10 + t;               // i1loc*4 + r2
            const float4 ov = *(const float4*)&o2[((ir >> 2) * 4 + j3s) * 20 + (ir & 3) * 4];
            const float w = c1r[t];
            a0 = fmaf(ov.x, w, a0); a1 = fmaf(ov.y, w, a1);
            a2 = fmaf(ov.z, w, a2); a3 = fmaf(ov.w, w, a3);
        }
        part1T[qs * 260 + (0 * 4 + j3s) * 16 + rc1] = a0;   // j2=0..3
        part1T[qs * 260 + (1 * 4 + j3s) * 16 + rc1] = a1;
        part1T[qs * 260 + (2 * 4 + j3s) * 16 + rc1] = a2;
        part1T[qs * 260 + (3 * 4 + j3s) * 16 + rc1] = a3;
    }
    __syncthreads();
    o1s[tid] = part1T[tid] + part1T[260 + tid] + part1T[520 + tid] + part1T[780 + tid];
    __syncthreads();

    // ---- stage 0 (this split's contribution): 3 columns/thread, atomic ----
    {
        const int j23 = tid & 15, j1 = (tid >> 4) & 3, j0g = tid >> 6;
        float a0 = 0.f, a1 = 0.f, a2 = 0.f;
        #pragma unroll
        for (int r1 = 0; r1 < 4; ++r1) {
            const float ov = o1s[j23 * 16 + r1 * 4 + j1];
            const int kb = OFF0 + (i0 * 4 + r1) * 12 + j0g * 3;
            a0 = fmaf(ov, ker[kb + 0], a0);
            a1 = fmaf(ov, ker[kb + 1], a1);
            a2 = fmaf(ov, ker[kb + 2], a2);
        }
        float* mrow = mx + (size_t)sample * 768;
        atomicAdd(&mrow[(j0g * 3 + 0) * 64 + j1 * 16 + j23], a0);
        atomicAdd(&mrow[(j0g * 3 + 1) * 64 + j1 * 16 + j23], a1);
        atomicAdd(&mrow[(j0g * 3 + 2) * 64 + j1 * 16 + j23], a2);
    }
}

// ---------------------------------------------------------------------------
// Phase 2: sequential GRU, one WG (512 thr) per sample.
// z/r weights: fp16 registers (128 h2/thread).
// hh weights: fp16 LDS, 16B-chunk-interleaved [k>>3][col][8] -> consecutive
// lanes read consecutive 16B chunks => conflict-free ds_read_b128.
// ---------------------------------------------------------------------------
__global__ __launch_bounds__(512) void gru_kernel(const float* __restrict__ mx,
                                                  const float* __restrict__ rk,
                                                  const float* __restrict__ cls_w,
                                                  const float* __restrict__ cls_b,
                                                  float* __restrict__ out) {
    __shared__ __align__(16) u16 wb[256 * 256];      // 128 KB, [chunk=k>>3][col][8]
    __shared__ float h32[256];
    __shared__ float zbuf[256];
    __shared__ float partB[256];
    __shared__ __align__(16) u16 h16[256];
    __shared__ __align__(16) u16 rh16[256];

    const int tid = threadIdx.x;
    const int b = blockIdx.x;
    const int cb = tid & 255, seg = tid >> 8;

    // ---- z/r column `tid` -> registers (fp16), lane-coalesced ----
    h2 wA[128];
    #pragma unroll
    for (int j = 0; j < 128; ++j) {
        h2 w;
        w.x = (_Float16)rk[(2 * j) * 768 + tid];
        w.y = (_Float16)rk[(2 * j + 1) * 768 + tid];
        wA[j] = w;
    }
    // ---- hh weights -> LDS, chunk-interleaved ----
    for (int k2 = 0; k2 < 128; ++k2) {
        const int k = seg * 128 + k2;
        wb[((k >> 3) * 256 + cb) * 8 + (k & 7)] =
            __builtin_bit_cast(u16, (_Float16)rk[k * 768 + 512 + cb]);
    }
    if (tid < 256) { h32[tid] = 0.f; h16[tid] = 0; }
    __syncthreads();

    const float* mxb = mx + (size_t)b * T_STEPS * 768;
    float mA = mxb[tid];
    float mB = mxb[512 + cb];

    for (int t = 0; t < T_STEPS; ++t) {
        float mA_n = 0.f, mB_n = 0.f;
        if (t + 1 < T_STEPS) {
            const float* nx = mxb + (t + 1) * 768;
            mA_n = nx[tid];
            mB_n = nx[512 + cb];
        }

        // ---- phase A: one z/r column per thread, 4 independent chains ----
        {
            float a0 = 0.f, a1 = 0.f, a2 = 0.f, a3 = 0.f;
            const uint4* hp = (const uint4*)h16;     // uniform -> broadcast
            #pragma unroll
            for (int j = 0; j < 32; ++j) {
                const uint4 u = hp[j];
                a0 = dot2(wA[4 * j + 0], __builtin_bit_cast(h2, u.x), a0);
                a1 = dot2(wA[4 * j + 1], __builtin_bit_cast(h2, u.y), a1);
                a2 = dot2(wA[4 * j + 2], __builtin_bit_cast(h2, u.z), a2);
                a3 = dot2(wA[4 * j + 3], __builtin_bit_cast(h2, u.w), a3);
            }
            const float v = mA + ((a0 + a1) + (a2 + a3));
            const float g = fminf(fmaxf(v * (1.f / 6.f) + 0.5f, 0.f), 1.f);
            if (tid < 256) zbuf[tid] = g;
            else ((_Float16*)rh16)[cb] = (_Float16)(g * h32[cb]);
        }
        __syncthreads();

        // ---- phase B: 2 threads per hh column; conflict-free LDS reads ----
        {
            float a0 = 0.f, a1 = 0.f, a2 = 0.f, a3 = 0.f;
            const uint4* wp = (const uint4*)wb;
            const uint4* rp = (const uint4*)rh16;
            #pragma unroll
            for (int j = 0; j < 16; ++j) {
                const int chunk = seg * 16 + j;
                const uint4 w = wp[chunk * 256 + cb];
                const uint4 r = rp[chunk];
                a0 = dot2(__builtin_bit_cast(h2, w.x), __builtin_bit_cast(h2, r.x), a0);
                a1 = dot2(__builtin_bit_cast(h2, w.y), __builtin_bit_cast(h2, r.y), a1);
                a2 = dot2(__builtin_bit_cast(h2, w.z), __builtin_bit_cast(h2, r.z), a2);
                a3 = dot2(__builtin_bit_cast(h2, w.w), __builtin_bit_cast(h2, r.w), a3);
            }
            const float acc = (a0 + a1) + (a2 + a3);
            if (seg) partB[cb] = acc;
            __syncthreads();
            if (!seg) {
                const float s = mB + acc + partB[cb];
                const float hh = tanhf(s);
                const float z = zbuf[cb];
                const float hn = z * h32[cb] + (1.f - z) * hh;
                h32[cb] = hn;
                h16[cb] = __builtin_bit_cast(u16, (_Float16)hn);
            }
        }
        __syncthreads();
        mA = mA_n; mB = mB_n;
    }

    // ---- classifier ----
    if (tid < 11) {
        float acc = cls_b[tid];
        const float* w = cls_w + tid * 256;
        #pragma unroll 4
        for (int i = 0; i < 256; ++i) acc = fmaf(h32[i], w[i], acc);
        out[b * 11 + tid] = acc;
    }
}

// ---------------------------------------------------------------------------
extern "C" void kernel_launch(void* const* d_in, const int* in_sizes, int n_in,
                              void* d_out, int out_size, void* d_ws, size_t ws_size,
                              hipStream_t stream) {
    const float* x     = (const float*)d_in[0];   // [32][40][57600]
    const float* ker   = (const float*)d_in[1];   // [3232]
    const float* rk    = (const float*)d_in[2];   // [256][768]
    const float* bias  = (const float*)d_in[3];   // [768]
    const float* cls_w = (const float*)d_in[4];   // [11][256]
    const float* cls_b = (const float*)d_in[5];   // [11]
    float* outp = (float*)d_out;                  // [32][11]

    float* mx = (float*)d_ws;                     // 1280*768 floats

    init_mx<<<BATCH * T_STEPS, 768, 0, stream>>>(bias, mx);
    tt_kernel<<<BATCH * T_STEPS * 8 * 2, 256, 0, stream>>>(x, ker, mx);
    gru_kernel<<<BATCH, 512, 0, stream>>>(mx, rk, cls_w, cls_b, outp);
}